// Round 10
// baseline (3002.514 us; speedup 1.0000x reference)
//
#include <hip/hip_runtime.h>
#include <hip/hip_bf16.h>
#include <stdint.h>

// MultiHeadedSelfAttention: B=2, L=4096, D=1024, H=1. fp32 inputs, FP32 OUTPUT.
// Round 10: the posted reference, exact-fp32 pipeline (= round 6), with the
// single fix: d_out is written as FLOAT32. Evidence: threshold == 2%*max|ref|
// exactly (no bf16 quantum); ~0.31 absmax invariant across 4 different
// functions = output-encoding mismatch signature; contract says output dtype
// follows the reference (float32), verified empirically for the inputs.
//
// Per batch b:
//   1. Q  = x_b @ Wq^T            (4096x1024)  fp32
//   2. Kp = x_b @ Wk^T            (4096x1024)  fp32
//   3. Vt = Wv @ x_b^T            (1024x4096)  fp32
//   4. S  = Q @ Kp^T / 32         (4096x4096)  fp32
//   5. softmax rows of S in place (fp32)
//   6. O  = S @ Vt^T              (4096x1024)  fp32, into Q (dead)
//   7. out_b = O @ Wo^T -> FP32 d_out
// ws (fp32 units): Q 4M | Kp 4M | Vt 4M | S 16M  = 28M f32 = 112 MiB.

typedef unsigned short u16;

// C(MxN) = scale * A(MxK, lda) @ B(NxK, ldb)^T. fp32 in/out.
// Tiles: 64x64, BK=16. 256 threads, 4x4 outputs each. All dims divide evenly.
__global__ __launch_bounds__(256)
void sgemm_nt(const float* __restrict__ A, const float* __restrict__ B,
              float* __restrict__ C, int K, int lda, int ldb, int ldc,
              float scale) {
  __shared__ __align__(16) float Ask[16][68];
  __shared__ __align__(16) float Bsk[16][68];

  const int tid = threadIdx.x;
  const int tx = tid & 15;        // output col group
  const int ty = tid >> 4;        // output row group
  const int r  = tid >> 2;        // staging row 0..63
  const int c4 = (tid & 3) * 4;   // staging k-offset 0,4,8,12

  const long long tileM = (long long)blockIdx.y * 64;
  const long long tileN = (long long)blockIdx.x * 64;

  const float* Ap = A + (tileM + r) * lda + c4;
  const float* Bp = B + (tileN + r) * ldb + c4;

  float acc[4][4];
#pragma unroll
  for (int i = 0; i < 4; ++i)
#pragma unroll
    for (int j = 0; j < 4; ++j) acc[i][j] = 0.f;

  for (int k0 = 0; k0 < K; k0 += 16) {
    float4 av = *(const float4*)(Ap + k0);
    float4 bv = *(const float4*)(Bp + k0);
    Ask[c4 + 0][r] = av.x; Ask[c4 + 1][r] = av.y;
    Ask[c4 + 2][r] = av.z; Ask[c4 + 3][r] = av.w;
    Bsk[c4 + 0][r] = bv.x; Bsk[c4 + 1][r] = bv.y;
    Bsk[c4 + 2][r] = bv.z; Bsk[c4 + 3][r] = bv.w;
    __syncthreads();

#pragma unroll
    for (int kk = 0; kk < 16; ++kk) {
      float4 a4 = *(const float4*)&Ask[kk][ty * 4];
      float4 b4 = *(const float4*)&Bsk[kk][tx * 4];
      float a[4] = {a4.x, a4.y, a4.z, a4.w};
      float b[4] = {b4.x, b4.y, b4.z, b4.w};
#pragma unroll
      for (int i = 0; i < 4; ++i)
#pragma unroll
        for (int j = 0; j < 4; ++j) acc[i][j] = fmaf(a[i], b[j], acc[i][j]);
    }
    __syncthreads();
  }

#pragma unroll
  for (int i = 0; i < 4; ++i) {
    const long long row = tileM + ty * 4 + i;
#pragma unroll
    for (int j = 0; j < 4; ++j) {
      const long long col = tileN + tx * 4 + j;
      C[row * ldc + col] = acc[i][j] * scale;
    }
  }
}

// In-place fp32 row softmax over 4096 columns. grid = rows, block = 256.
__global__ __launch_bounds__(256)
void softmax_rows_f32(float* __restrict__ S) {
  const int tid = threadIdx.x;
  float* rp = S + (long long)blockIdx.x * 4096;

  float v[16];
#pragma unroll
  for (int q = 0; q < 4; ++q) {
    float4 t = ((const float4*)rp)[tid * 4 + q];
    v[q * 4 + 0] = t.x; v[q * 4 + 1] = t.y; v[q * 4 + 2] = t.z; v[q * 4 + 3] = t.w;
  }

  float m = v[0];
#pragma unroll
  for (int i = 1; i < 16; ++i) m = fmaxf(m, v[i]);
#pragma unroll
  for (int o = 32; o > 0; o >>= 1) m = fmaxf(m, __shfl_xor(m, o));
  __shared__ float redm[4];
  __shared__ float reds[4];
  const int wave = tid >> 6;
  if ((tid & 63) == 0) redm[wave] = m;
  __syncthreads();
  m = fmaxf(fmaxf(redm[0], redm[1]), fmaxf(redm[2], redm[3]));

  float s = 0.f;
#pragma unroll
  for (int i = 0; i < 16; ++i) {
    v[i] = __expf(v[i] - m);
    s += v[i];
  }
#pragma unroll
  for (int o = 32; o > 0; o >>= 1) s += __shfl_xor(s, o);
  if ((tid & 63) == 0) reds[wave] = s;
  __syncthreads();
  s = (reds[0] + reds[1]) + (reds[2] + reds[3]);
  const float inv = 1.0f / s;

#pragma unroll
  for (int q = 0; q < 4; ++q) {
    float4 t = {v[q * 4 + 0] * inv, v[q * 4 + 1] * inv,
                v[q * 4 + 2] * inv, v[q * 4 + 3] * inv};
    ((float4*)rp)[tid * 4 + q] = t;
  }
}

extern "C" void kernel_launch(void* const* d_in, const int* in_sizes, int n_in,
                              void* d_out, int out_size, void* d_ws, size_t ws_size,
                              hipStream_t stream) {
  const float* x  = (const float*)d_in[0];   // (2,4096,1024) fp32, batch-major
  const float* Wq = (const float*)d_in[1];   // (1024,1024) fp32 (out,in)
  const float* Wk = (const float*)d_in[2];
  const float* Wv = (const float*)d_in[3];
  const float* Wo = (const float*)d_in[4];
  float* out = (float*)d_out;                // (2,4096,1024) FP32

  float* Q  = (float*)d_ws;                  // 4096x1024
  float* Kp = Q  + 4194304;                  // 4096x1024
  float* Vt = Kp + 4194304;                  // 1024x4096
  float* S  = Vt + 4194304;                  // 4096x4096
  float* O  = Q;                             // alias: Q dead after scores GEMM

  const dim3 blk(256);

  for (int b = 0; b < 2; ++b) {
    const float* xb = x + (size_t)b * 4194304;
    float* outb = out + (size_t)b * 4194304;

    // 1,2: Q = x@Wq^T, Kp = x@Wk^T   (M=4096, N=1024, K=1024)
    sgemm_nt<<<dim3(16, 64), blk, 0, stream>>>(xb, Wq, Q,  1024, 1024, 1024, 1024, 1.f);
    sgemm_nt<<<dim3(16, 64), blk, 0, stream>>>(xb, Wk, Kp, 1024, 1024, 1024, 1024, 1.f);
    // 3: Vt = Wv@x^T   (M=1024, N=4096, K=1024)
    sgemm_nt<<<dim3(64, 16), blk, 0, stream>>>(Wv, xb, Vt, 1024, 1024, 1024, 4096, 1.f);
    // 4: S = Q@Kp^T / 32   (M=N=4096, K=1024)
    sgemm_nt<<<dim3(64, 64), blk, 0, stream>>>(Q, Kp, S, 1024, 1024, 1024, 4096, 0.03125f);
    // 5: softmax rows
    softmax_rows_f32<<<dim3(4096), blk, 0, stream>>>(S);
    // 6: O = P@V = S @ Vt^T   (M=4096, N=1024, K=4096) -> into Q (dead)
    sgemm_nt<<<dim3(16, 64), blk, 0, stream>>>(S, Vt, O, 4096, 4096, 4096, 1024, 1.f);
    // 7: out_b = O@Wo^T   (M=4096, N=1024, K=1024), FP32 store
    sgemm_nt<<<dim3(16, 64), blk, 0, stream>>>(O, Wo, outb, 1024, 1024, 1024, 1024, 1.f);
  }
}

// Round 11
// 656.606 us; speedup vs baseline: 4.5728x; 4.5728x over previous
//
#include <hip/hip_runtime.h>
#include <hip/hip_bf16.h>
#include <stdint.h>

// MultiHeadedSelfAttention: B=2, L=4096, D=1024, H=1. fp32 inputs, FP32 output.
// Round 11: bf16-MFMA pipeline (rounds 2-4 machinery, proven function-identical
// to the passing fp32 pipeline) with the round-10 fix: final store is fp32.
//
// Per batch b (batch-serial, ws 58 MiB):
//   0. cast x_b, Wq, Wk, Wv -> bf16 into the S region (dead until step 4)
//   1. Q  = x_b @ Wq^T          (4096x1024, K=1024)  bf16 MFMA, fp32 accum
//   2. Kp = x_b @ Wk^T          (4096x1024)
//   3. Vt = Wv @ x_b^T          (1024x4096)
//   4. S  = Q @ Kp^T / 32       (4096x4096) bf16 -> overwrites cast scratch
//   5. softmax rows in place (bf16 I/O, fp32 math)
//   6. O  = P @ V  (BT-gemm with Vt, ldb=4096) -> into Q (dead)
//   7. out_b = O @ Wo^T -> FP32 d_out
// ws layout (u16): Q 4.19M | Kp 4.19M | Vt 4.19M | Wob 1.05M | S 16.78M = 58 MiB.

typedef unsigned short u16;
typedef short short8 __attribute__((ext_vector_type(8)));
typedef float f32x4 __attribute__((ext_vector_type(4)));

__device__ __forceinline__ void async_ld16(void* lds, const void* g) {
  __builtin_amdgcn_global_load_lds(
      (const __attribute__((address_space(1))) unsigned int*)g,
      (__attribute__((address_space(3))) unsigned int*)lds,
      16, 0, 0);
}

__device__ __forceinline__ u16 f2bf(float f) {  // RNE
  unsigned u = __float_as_uint(f);
  u += 0x7FFFu + ((u >> 16) & 1u);
  return (u16)(u >> 16);
}

// fp32 -> bf16, 8 elems/thread. n must be a multiple of 8 (true here).
__global__ __launch_bounds__(256)
void cast_f32_bf16(const float* __restrict__ in, u16* __restrict__ out, int n) {
  const int i = (blockIdx.x * 256 + threadIdx.x) * 8;
  if (i >= n) return;
  float4 a = ((const float4*)(in + i))[0];
  float4 b = ((const float4*)(in + i))[1];
  uint4 o;
  o.x = (unsigned)f2bf(a.x) | ((unsigned)f2bf(a.y) << 16);
  o.y = (unsigned)f2bf(a.z) | ((unsigned)f2bf(a.w) << 16);
  o.z = (unsigned)f2bf(b.x) | ((unsigned)f2bf(b.y) << 16);
  o.w = (unsigned)f2bf(b.z) | ((unsigned)f2bf(b.w) << 16);
  *(uint4*)(out + i) = o;
}

#define BM 128
#define BN 128
#define BK 32

// C(MxN, ldc) = scale * A(MxK, lda) @ Bt(NxK, ldb)^T. A,Bt bf16; fp32 accum.
// C stored bf16 (store_f32=0) or fp32 (store_f32=1).
// grid: (N/128, M/128); block: 256 threads = 4 waves in 2x2. [m97 structure]
__global__ __launch_bounds__(256)
void gemm_bt(const u16* __restrict__ A, const u16* __restrict__ Bt,
             void* __restrict__ Cv, int K, int lda, int ldb, int ldc,
             float scale, int store_f32) {
  __shared__ u16 As[BM * BK];
  __shared__ u16 Bs[BN * BK];

  const int tid  = threadIdx.x;
  const int wave = tid >> 6;
  const int lane = tid & 63;
  const int wm   = wave >> 1;      // 0..1: wave row in 2x2
  const int wn   = wave & 1;       // 0..1: wave col
  const int r15  = lane & 15;
  const int q4   = lane >> 4;      // 0..3

  const int tileM = blockIdx.y * BM;
  const int tileN = blockIdx.x * BN;

  // staging: thread covers 16B (8 bf16); tile = 128x32 contiguous, 2 rounds
  const int srow = tid >> 2;             // 0..63
  const int scol = (tid & 3) * 8;        // 0,8,16,24

  const u16* Aptr = A + (long long)tileM * lda;
  const u16* Bptr = Bt + (long long)tileN * ldb;

  f32x4 zero = {0.f, 0.f, 0.f, 0.f};
  f32x4 acc[4][4];
#pragma unroll
  for (int i = 0; i < 4; ++i)
#pragma unroll
    for (int j = 0; j < 4; ++j) acc[i][j] = zero;

  for (int k0 = 0; k0 < K; k0 += BK) {
    async_ld16(&As[tid * 8],        Aptr + (long long)srow * lda + k0 + scol);
    async_ld16(&As[2048 + tid * 8], Aptr + (long long)(srow + 64) * lda + k0 + scol);
    async_ld16(&Bs[tid * 8],        Bptr + (long long)srow * ldb + k0 + scol);
    async_ld16(&Bs[2048 + tid * 8], Bptr + (long long)(srow + 64) * ldb + k0 + scol);
    __syncthreads();

    short8 af[4], bf[4];
#pragma unroll
    for (int i = 0; i < 4; ++i)
      af[i] = *(const short8*)&As[(wm * 64 + i * 16 + r15) * BK + q4 * 8];
#pragma unroll
    for (int i = 0; i < 4; ++i)
      bf[i] = *(const short8*)&Bs[(wn * 64 + i * 16 + r15) * BK + q4 * 8];

#pragma unroll
    for (int i = 0; i < 4; ++i)
#pragma unroll
      for (int j = 0; j < 4; ++j)
        acc[i][j] = __builtin_amdgcn_mfma_f32_16x16x32_bf16(af[i], bf[j], acc[i][j], 0, 0, 0);

    __syncthreads();
  }

  // epilogue: C/D layout col = lane&15, row = q4*4 + reg
  // [verified end-to-end: rounds 2-4 bit-match the passing fp32 pipeline]
#pragma unroll
  for (int i = 0; i < 4; ++i) {
#pragma unroll
    for (int j = 0; j < 4; ++j) {
      const int col = tileN + wn * 64 + j * 16 + r15;
#pragma unroll
      for (int r = 0; r < 4; ++r) {
        const int row = tileM + wm * 64 + i * 16 + q4 * 4 + r;
        const float val = acc[i][j][r] * scale;
        if (store_f32) ((float*)Cv)[(long long)row * ldc + col] = val;
        else           ((u16*)Cv)[(long long)row * ldc + col] = f2bf(val);
      }
    }
  }
}

// In-place row softmax over 4096 bf16 columns. grid = rows, block = 256.
__global__ __launch_bounds__(256)
void softmax_rows(u16* __restrict__ S) {
  const int tid = threadIdx.x;
  u16* rp = S + (long long)blockIdx.x * 4096;

  uint4 a = ((const uint4*)rp)[tid * 2];
  uint4 b = ((const uint4*)rp)[tid * 2 + 1];
  unsigned w[8] = {a.x, a.y, a.z, a.w, b.x, b.y, b.z, b.w};
  float v[16];
#pragma unroll
  for (int i = 0; i < 8; ++i) {
    v[2 * i]     = __uint_as_float(w[i] << 16);
    v[2 * i + 1] = __uint_as_float(w[i] & 0xFFFF0000u);
  }

  float m = v[0];
#pragma unroll
  for (int i = 1; i < 16; ++i) m = fmaxf(m, v[i]);
#pragma unroll
  for (int o = 32; o > 0; o >>= 1) m = fmaxf(m, __shfl_xor(m, o));
  __shared__ float redm[4];
  __shared__ float reds[4];
  const int wave = tid >> 6;
  if ((tid & 63) == 0) redm[wave] = m;
  __syncthreads();
  m = fmaxf(fmaxf(redm[0], redm[1]), fmaxf(redm[2], redm[3]));

  float s = 0.f;
#pragma unroll
  for (int i = 0; i < 16; ++i) {
    v[i] = __expf(v[i] - m);
    s += v[i];
  }
#pragma unroll
  for (int o = 32; o > 0; o >>= 1) s += __shfl_xor(s, o);
  if ((tid & 63) == 0) reds[wave] = s;
  __syncthreads();
  s = (reds[0] + reds[1]) + (reds[2] + reds[3]);
  const float inv = 1.0f / s;

#pragma unroll
  for (int i = 0; i < 8; ++i)
    w[i] = (unsigned)f2bf(v[2 * i] * inv) | ((unsigned)f2bf(v[2 * i + 1] * inv) << 16);
  uint4 oa = {w[0], w[1], w[2], w[3]};
  uint4 ob = {w[4], w[5], w[6], w[7]};
  ((uint4*)rp)[tid * 2] = oa;
  ((uint4*)rp)[tid * 2 + 1] = ob;
}

extern "C" void kernel_launch(void* const* d_in, const int* in_sizes, int n_in,
                              void* d_out, int out_size, void* d_ws, size_t ws_size,
                              hipStream_t stream) {
  const float* x  = (const float*)d_in[0];   // (2,4096,1024) fp32, batch-major
  const float* Wq = (const float*)d_in[1];   // (1024,1024) fp32 (out,in)
  const float* Wk = (const float*)d_in[2];
  const float* Wv = (const float*)d_in[3];
  const float* Wo = (const float*)d_in[4];
  float* out = (float*)d_out;                // (2,4096,1024) FP32

  // ws layout (u16 units) — 30,408,704 u16 = 58.0 MiB total
  u16* Q   = (u16*)d_ws;                     // 4096x1024
  u16* Kp  = Q   + 4194304;                  // 4096x1024
  u16* Vt  = Kp  + 4194304;                  // 1024x4096 (Vt[e][l] = V[l][e])
  u16* Wob = Vt  + 4194304;                  // 1024x1024 (persists across batches)
  u16* S   = Wob + 1048576;                  // 4096x4096 (one batch)
  // cast scratch aliased INSIDE S (dead once S is written):
  u16* xb  = S;                              // 4096x1024
  u16* Wqb = S  + 4194304;                   // 1024x1024
  u16* Wkb = Wqb + 1048576;
  u16* Wvb = Wkb + 1048576;
  u16* O   = Q;                              // alias: Q dead after scores GEMM

  const dim3 blk(256);

  cast_f32_bf16<<<dim3(512), blk, 0, stream>>>(Wo, Wob, 1048576);

  for (int b = 0; b < 2; ++b) {
    const float* xf = x + (size_t)b * 4194304;
    float* outb = out + (size_t)b * 4194304;

    // 0: casts (into S region — dead until step 4)
    cast_f32_bf16<<<dim3(2048), blk, 0, stream>>>(xf, xb, 4194304);
    cast_f32_bf16<<<dim3(512),  blk, 0, stream>>>(Wq, Wqb, 1048576);
    cast_f32_bf16<<<dim3(512),  blk, 0, stream>>>(Wk, Wkb, 1048576);
    cast_f32_bf16<<<dim3(512),  blk, 0, stream>>>(Wv, Wvb, 1048576);

    // 1,2: Q = x@Wq^T, Kp = x@Wk^T   (M=4096, N=1024, K=1024)
    gemm_bt<<<dim3(8, 32), blk, 0, stream>>>(xb, Wqb, Q,  1024, 1024, 1024, 1024, 1.f, 0);
    gemm_bt<<<dim3(8, 32), blk, 0, stream>>>(xb, Wkb, Kp, 1024, 1024, 1024, 1024, 1.f, 0);
    // 3: Vt = Wv@x^T   (M=1024, N=4096, K=1024) -> ldc=4096
    gemm_bt<<<dim3(32, 8), blk, 0, stream>>>(Wvb, xb, Vt, 1024, 1024, 1024, 4096, 1.f, 0);
    // 4: S = Q @ Kp^T / 32   (M=N=4096, K=1024) — overwrites cast scratch (dead)
    gemm_bt<<<dim3(32, 32), blk, 0, stream>>>(Q, Kp, S, 1024, 1024, 1024, 4096, 0.03125f, 0);
    // 5: softmax in place, 4096 rows
    softmax_rows<<<dim3(4096), blk, 0, stream>>>(S);
    // 6: O = P @ V  == BT-gemm(A=P (4096x4096), Bt=Vt (1024x4096)) -> into Q (dead)
    gemm_bt<<<dim3(8, 32), blk, 0, stream>>>(S, Vt, O, 4096, 4096, 4096, 1024, 1.f, 0);
    // 7: out_b = O @ Wo^T   (M=4096, N=1024, K=1024), FP32 store
    gemm_bt<<<dim3(8, 32), blk, 0, stream>>>(O, Wob, outb, 1024, 1024, 1024, 1024, 1.f, 1);
  }
}

// Round 12
// 459.239 us; speedup vs baseline: 6.5380x; 1.4298x over previous
//
#include <hip/hip_runtime.h>
#include <hip/hip_bf16.h>
#include <stdint.h>

// MultiHeadedSelfAttention: B=2, L=4096, D=1024, H=1. fp32 inputs, FP32 output.
// Round 12: z/M-batched bf16-MFMA pipeline. Projections/final run as one
// M=8192 GEMM (2x blocks/CU); scores/PV run z=2 in one launch; casts hoisted.
//   0. cast x (8192x1024), Wq, Wk, Wv, Wo -> bf16 (once)
//   1. Q  = x @ Wq^T          (8192x1024, K=1024)   grid 512
//   2. Kp = x @ Wk^T          (8192x1024)            grid 512
//   3. Vt = Wv @ x^T          (1024x8192)            grid 512
//   4. S_z = Q_z @ Kp_z^T/32  (2x 4096x4096, K=1024) grid 2048
//   5. softmax rows (8192 rows)
//   6. O_z = P_z @ V_z        (BT with Vt+z*4096, ldb=8192) grid 512 -> into Q
//   7. out = O @ Wo^T -> FP32 d_out (M=8192)         grid 512
// ws (u16): xb 8.39M | W*b 4x1.05M | Q 8.39M | Kp 8.39M | Vt 8.39M | S 33.55M
// = 71,303,168 u16 = 136 MiB (layout proven safe in rounds 2-4).

typedef unsigned short u16;
typedef short short8 __attribute__((ext_vector_type(8)));
typedef float f32x4 __attribute__((ext_vector_type(4)));

__device__ __forceinline__ void async_ld16(void* lds, const void* g) {
  __builtin_amdgcn_global_load_lds(
      (const __attribute__((address_space(1))) unsigned int*)g,
      (__attribute__((address_space(3))) unsigned int*)lds,
      16, 0, 0);
}

__device__ __forceinline__ u16 f2bf(float f) {  // RNE
  unsigned u = __float_as_uint(f);
  u += 0x7FFFu + ((u >> 16) & 1u);
  return (u16)(u >> 16);
}

// fp32 -> bf16, 8 elems/thread. n must be a multiple of 8 (true here).
__global__ __launch_bounds__(256)
void cast_f32_bf16(const float* __restrict__ in, u16* __restrict__ out, int n) {
  const int i = (blockIdx.x * 256 + threadIdx.x) * 8;
  if (i >= n) return;
  float4 a = ((const float4*)(in + i))[0];
  float4 b = ((const float4*)(in + i))[1];
  uint4 o;
  o.x = (unsigned)f2bf(a.x) | ((unsigned)f2bf(a.y) << 16);
  o.y = (unsigned)f2bf(a.z) | ((unsigned)f2bf(a.w) << 16);
  o.z = (unsigned)f2bf(b.x) | ((unsigned)f2bf(b.y) << 16);
  o.w = (unsigned)f2bf(b.z) | ((unsigned)f2bf(b.w) << 16);
  *(uint4*)(out + i) = o;
}

#define BM 128
#define BN 128
#define BK 32

// C(MxN, ldc) = scale * A(MxK, lda) @ Bt(NxK, ldb)^T. A,Bt bf16; fp32 accum.
// z-strides sAz/sBz/sCz (elements) for batched launches.
// C stored bf16 (store_f32=0) or fp32 (store_f32=1).
// grid: (N/128, M/128, Z); block: 256 threads = 4 waves in 2x2. [m97 structure]
__global__ __launch_bounds__(256)
void gemm_bt(const u16* __restrict__ A, const u16* __restrict__ Bt,
             void* __restrict__ Cv, int K, int lda, int ldb, int ldc,
             long long sAz, long long sBz, long long sCz,
             float scale, int store_f32) {
  __shared__ u16 As[BM * BK];
  __shared__ u16 Bs[BN * BK];

  A  += (long long)blockIdx.z * sAz;
  Bt += (long long)blockIdx.z * sBz;

  const int tid  = threadIdx.x;
  const int wave = tid >> 6;
  const int lane = tid & 63;
  const int wm   = wave >> 1;      // 0..1: wave row in 2x2
  const int wn   = wave & 1;       // 0..1: wave col
  const int r15  = lane & 15;
  const int q4   = lane >> 4;      // 0..3

  const int tileM = blockIdx.y * BM;
  const int tileN = blockIdx.x * BN;

  // staging: thread covers 16B (8 bf16); tile = 128x32 contiguous, 2 rounds
  const int srow = tid >> 2;             // 0..63
  const int scol = (tid & 3) * 8;        // 0,8,16,24

  const u16* Aptr = A + (long long)tileM * lda;
  const u16* Bptr = Bt + (long long)tileN * ldb;

  f32x4 zero = {0.f, 0.f, 0.f, 0.f};
  f32x4 acc[4][4];
#pragma unroll
  for (int i = 0; i < 4; ++i)
#pragma unroll
    for (int j = 0; j < 4; ++j) acc[i][j] = zero;

  for (int k0 = 0; k0 < K; k0 += BK) {
    async_ld16(&As[tid * 8],        Aptr + (long long)srow * lda + k0 + scol);
    async_ld16(&As[2048 + tid * 8], Aptr + (long long)(srow + 64) * lda + k0 + scol);
    async_ld16(&Bs[tid * 8],        Bptr + (long long)srow * ldb + k0 + scol);
    async_ld16(&Bs[2048 + tid * 8], Bptr + (long long)(srow + 64) * ldb + k0 + scol);
    __syncthreads();

    short8 af[4], bf[4];
#pragma unroll
    for (int i = 0; i < 4; ++i)
      af[i] = *(const short8*)&As[(wm * 64 + i * 16 + r15) * BK + q4 * 8];
#pragma unroll
    for (int i = 0; i < 4; ++i)
      bf[i] = *(const short8*)&Bs[(wn * 64 + i * 16 + r15) * BK + q4 * 8];

#pragma unroll
    for (int i = 0; i < 4; ++i)
#pragma unroll
      for (int j = 0; j < 4; ++j)
        acc[i][j] = __builtin_amdgcn_mfma_f32_16x16x32_bf16(af[i], bf[j], acc[i][j], 0, 0, 0);

    __syncthreads();
  }

  // epilogue: C/D layout col = lane&15, row = q4*4 + reg  [e2e-verified]
#pragma unroll
  for (int i = 0; i < 4; ++i) {
#pragma unroll
    for (int j = 0; j < 4; ++j) {
      const int col = tileN + wn * 64 + j * 16 + r15;
#pragma unroll
      for (int r = 0; r < 4; ++r) {
        const int row = tileM + wm * 64 + i * 16 + q4 * 4 + r;
        const long long idx = (long long)blockIdx.z * sCz + (long long)row * ldc + col;
        const float val = acc[i][j][r] * scale;
        if (store_f32) ((float*)Cv)[idx] = val;
        else           ((u16*)Cv)[idx] = f2bf(val);
      }
    }
  }
}

// In-place row softmax over 4096 bf16 columns. grid = rows, block = 256.
__global__ __launch_bounds__(256)
void softmax_rows(u16* __restrict__ S) {
  const int tid = threadIdx.x;
  u16* rp = S + (long long)blockIdx.x * 4096;

  uint4 a = ((const uint4*)rp)[tid * 2];
  uint4 b = ((const uint4*)rp)[tid * 2 + 1];
  unsigned w[8] = {a.x, a.y, a.z, a.w, b.x, b.y, b.z, b.w};
  float v[16];
#pragma unroll
  for (int i = 0; i < 8; ++i) {
    v[2 * i]     = __uint_as_float(w[i] << 16);
    v[2 * i + 1] = __uint_as_float(w[i] & 0xFFFF0000u);
  }

  float m = v[0];
#pragma unroll
  for (int i = 1; i < 16; ++i) m = fmaxf(m, v[i]);
#pragma unroll
  for (int o = 32; o > 0; o >>= 1) m = fmaxf(m, __shfl_xor(m, o));
  __shared__ float redm[4];
  __shared__ float reds[4];
  const int wave = tid >> 6;
  if ((tid & 63) == 0) redm[wave] = m;
  __syncthreads();
  m = fmaxf(fmaxf(redm[0], redm[1]), fmaxf(redm[2], redm[3]));

  float s = 0.f;
#pragma unroll
  for (int i = 0; i < 16; ++i) {
    v[i] = __expf(v[i] - m);
    s += v[i];
  }
#pragma unroll
  for (int o = 32; o > 0; o >>= 1) s += __shfl_xor(s, o);
  if ((tid & 63) == 0) reds[wave] = s;
  __syncthreads();
  s = (reds[0] + reds[1]) + (reds[2] + reds[3]);
  const float inv = 1.0f / s;

#pragma unroll
  for (int i = 0; i < 8; ++i)
    w[i] = (unsigned)f2bf(v[2 * i] * inv) | ((unsigned)f2bf(v[2 * i + 1] * inv) << 16);
  uint4 oa = {w[0], w[1], w[2], w[3]};
  uint4 ob = {w[4], w[5], w[6], w[7]};
  ((uint4*)rp)[tid * 2] = oa;
  ((uint4*)rp)[tid * 2 + 1] = ob;
}

extern "C" void kernel_launch(void* const* d_in, const int* in_sizes, int n_in,
                              void* d_out, int out_size, void* d_ws, size_t ws_size,
                              hipStream_t stream) {
  const float* x  = (const float*)d_in[0];   // (2,4096,1024) fp32, batch-major
  const float* Wq = (const float*)d_in[1];   // (1024,1024) fp32 (out,in)
  const float* Wk = (const float*)d_in[2];
  const float* Wv = (const float*)d_in[3];
  const float* Wo = (const float*)d_in[4];
  float* out = (float*)d_out;                // (2,4096,1024) FP32

  // ws layout (u16 units) — 136 MiB total
  u16* xb  = (u16*)d_ws;                     // 8192x1024
  u16* Wqb = xb  + 8388608;                  // 1024x1024
  u16* Wkb = Wqb + 1048576;
  u16* Wvb = Wkb + 1048576;
  u16* Wob = Wvb + 1048576;
  u16* Q   = Wob + 1048576;                  // 8192x1024
  u16* Kp  = Q   + 8388608;                  // 8192x1024
  u16* Vt  = Kp  + 8388608;                  // 1024x8192 (Vt[e][b*4096+l])
  u16* S   = Vt  + 8388608;                  // 2 x 4096x4096
  u16* O   = Q;                              // alias: Q dead after scores GEMM

  const dim3 blk(256);

  // 0: casts (once)
  cast_f32_bf16<<<dim3(4096), blk, 0, stream>>>(x,  xb,  8388608);
  cast_f32_bf16<<<dim3(512),  blk, 0, stream>>>(Wq, Wqb, 1048576);
  cast_f32_bf16<<<dim3(512),  blk, 0, stream>>>(Wk, Wkb, 1048576);
  cast_f32_bf16<<<dim3(512),  blk, 0, stream>>>(Wv, Wvb, 1048576);
  cast_f32_bf16<<<dim3(512),  blk, 0, stream>>>(Wo, Wob, 1048576);

  // 1,2: Q = x@Wq^T, Kp = x@Wk^T   (M=8192, N=1024, K=1024), 512 blocks
  gemm_bt<<<dim3(8, 64, 1), blk, 0, stream>>>(xb, Wqb, Q, 1024, 1024, 1024, 1024,
                                              0, 0, 0, 1.f, 0);
  gemm_bt<<<dim3(8, 64, 1), blk, 0, stream>>>(xb, Wkb, Kp, 1024, 1024, 1024, 1024,
                                              0, 0, 0, 1.f, 0);
  // 3: Vt = Wv@x^T   (M=1024, N=8192, K=1024) -> ldc=8192, 512 blocks
  gemm_bt<<<dim3(64, 8, 1), blk, 0, stream>>>(Wvb, xb, Vt, 1024, 1024, 1024, 8192,
                                              0, 0, 0, 1.f, 0);
  // 4: S_z = Q_z @ Kp_z^T / 32   (M=N=4096, K=1024), z=2, 2048 blocks
  gemm_bt<<<dim3(32, 32, 2), blk, 0, stream>>>(Q, Kp, S, 1024, 1024, 1024, 4096,
                                               4194304LL, 4194304LL, 16777216LL,
                                               0.03125f, 0);
  // 5: softmax in place, 8192 rows
  softmax_rows<<<dim3(8192), blk, 0, stream>>>(S);
  // 6: O_z = P_z @ V_z == BT(A=S_z (4096x4096), Bt=Vt+z*4096, ldb=8192), 512 blocks
  gemm_bt<<<dim3(8, 32, 2), blk, 0, stream>>>(S, Vt, O, 4096, 4096, 8192, 1024,
                                              16777216LL, 4096LL, 4194304LL, 1.f, 0);
  // 7: out = O @ Wo^T   (M=8192, N=1024, K=1024), FP32 store, 512 blocks
  gemm_bt<<<dim3(8, 64, 1), blk, 0, stream>>>(O, Wob, out, 1024, 1024, 1024, 1024,
                                              0, 0, 0, 1.f, 1);
}